// Round 9
// baseline (57.725 us; speedup 1.0000x reference)
//
#include <hip/hip_runtime.h>
#include <math.h>

// (b,n,h,d) = (4,8192,8,64), fp32.
// Groups: i=0: g=3,r=1,off=0,hmin=0,seg=2048  -> 8192 covered pos/b
//         i=1: g=3,r=2,off=1,hmin=3,seg=4096  -> 4096 covered pos/b (pos%2==1)
//         i=2: g=2,r=4,off=2,hmin=6,seg=8192  -> 2048 covered pos/b (pos%4==2)
#define NB 4
#define NN 8192
#define NH 8
#define ND 64
#define ROWF (NH * ND)          // 512 floats = 2KB per (b,pos) row
#define NPART_STRIDE 192        // per-WAVE partial: g*64 floats (max g=3)
#define N_BLOCKS_P1 1792        // uniform 7 blocks/CU
#define N_WAVES_P1  (N_BLOCKS_P1 * 4)

// R9: sub-group = HEAD (not position). R1-R8 falsified every MLP/occupancy
// theory (13-52% occ, 2-18 in-flight, 4 load engines -> all ~56us); pass3
// moves same-residency bytes at ~19 TB/s with single-contiguous-segment
// instructions. Here every pass1 load/store is 1 contiguous segment:
// Q = 1KB/instr (per-lane distinct, one waste head), K/V = 256B broadcast
// rows (coalescer dedups), store = 768B contiguous. Butterfly shrinks to
// 3 dots/lane; cross-subgroup reduce eliminated (one lane owns one (q,d)).

__device__ __forceinline__ float dot4(float4 a, float4 b) {
    return a.x * b.x + a.y * b.y + a.z * b.z + a.w * b.w;
}

// groups 0/1 (g=3): one position per iteration, 8 positions per wave.
template<int HOFF>   // head offset in floats: 0 (g0: h0-2) or 192 (g1: h3-5)
__device__ __forceinline__ void pass1_g3(
    const float* __restrict__ Q, const float* __restrict__ K,
    const float* __restrict__ V, float* __restrict__ out,
    float* __restrict__ partials,
    int b, int cw, int wid, int r, int off, int seglen)
{
    const int lane = threadIdx.x & 63;
    const int sg   = lane >> 4;     // local head q = sg (sg==3 is waste)
    const int l15  = lane & 15;     // lane owns d in [4*l15, 4*l15+4)

    float xs0 = 0.f, xs1 = 0.f, xs2 = 0.f, xs3 = 0.f;

    #pragma unroll 2
    for (int t = 0; t < 8; ++t) {
        const int j   = cw * 8 + t;
        const int pos = (j >> 11) * seglen + off + (j & 2047) * r;
        const size_t rb = ((size_t)b * NN + pos) * ROWF;

        // Q: per-lane distinct, fully contiguous 1KB (h0..h3 of the slice)
        const float4 qv = *(const float4*)(Q + rb + HOFF + 4 * lane);
        // K,V rows: 256B broadcast loads (same 16 float4s to all sub-groups)
        const float4 k0 = *(const float4*)(K + rb + HOFF + 0 * ND + 4 * l15);
        const float4 k1 = *(const float4*)(K + rb + HOFF + 1 * ND + 4 * l15);
        const float4 k2 = *(const float4*)(K + rb + HOFF + 2 * ND + 4 * l15);
        const float4 v0 = *(const float4*)(V + rb + HOFF + 0 * ND + 4 * l15);
        const float4 v1 = *(const float4*)(V + rb + HOFF + 1 * ND + 4 * l15);
        const float4 v2 = *(const float4*)(V + rb + HOFF + 2 * ND + 4 * l15);

        // 3 partial dots for q = sg; butterfly over the 16 lanes of this sg
        float s0 = dot4(qv, k0), s1 = dot4(qv, k1), s2 = dot4(qv, k2);
        #pragma unroll
        for (int o = 8; o >= 1; o >>= 1) {
            s0 += __shfl_xor(s0, o);
            s1 += __shfl_xor(s1, o);
            s2 += __shfl_xor(s2, o);
        }

        // softmax over k (per-lane, redundant within the sub-group)
        s0 *= 0.125f; s1 *= 0.125f; s2 *= 0.125f;
        const float m  = fmaxf(s0, fmaxf(s1, s2));
        const float e0 = __expf(s0 - m), e1 = __expf(s1 - m), e2 = __expf(s2 - m);
        const float rs = 1.f / (e0 + e1 + e2);
        const float w0 = e0 * rs, w1 = e1 * rs, w2 = e2 * rs;

        const float xe0 = w0 * v0.x + w1 * v1.x + w2 * v2.x;
        const float xe1 = w0 * v0.y + w1 * v1.y + w2 * v2.y;
        const float xe2 = w0 * v0.z + w1 * v1.z + w2 * v2.z;
        const float xe3 = w0 * v0.w + w1 * v1.w + w2 * v2.w;

        if (sg < 3)   // single contiguous 768B store (lanes 0-47)
            *(float4*)(out + rb + HOFF + 4 * lane) = make_float4(xe0, xe1, xe2, xe3);
        xs0 += xe0; xs1 += xe1; xs2 += xe2; xs3 += xe3;
    }

    if (sg < 3)       // lane owns (q=sg, d-slice) exclusively: direct write
        *(float4*)(partials + (size_t)wid * NPART_STRIDE + sg * 64 + 4 * l15) =
            make_float4(xs0, xs1, xs2, xs3);
}

// group 2 (g=2): two positions per iteration (half-wave each), 8 pos per wave.
__device__ __forceinline__ void pass1_g2(
    const float* __restrict__ Q, const float* __restrict__ K,
    const float* __restrict__ V, float* __restrict__ out,
    float* __restrict__ partials, int b, int cw, int wid)
{
    const int lane = threadIdx.x & 63;
    const int half = lane >> 5;          // which of the 2 positions
    const int sg2  = (lane >> 4) & 1;    // local head q (h6+sg2)
    const int l15  = lane & 15;
    const int l31  = lane & 31;

    float xs0 = 0.f, xs1 = 0.f, xs2 = 0.f, xs3 = 0.f;

    #pragma unroll 2
    for (int t = 0; t < 4; ++t) {
        const int j   = cw * 8 + t * 2 + half;   // dilated index, same for 32 lanes
        const int pos = 2 + 4 * j;               // seglen 8192: single segment
        const size_t rb = ((size_t)b * NN + pos) * ROWF + 384;  // h6 offset

        const float4 qv = *(const float4*)(Q + rb + 4 * l31);   // 2x512B contiguous
        const float4 k0 = *(const float4*)(K + rb + 0 * ND + 4 * l15);
        const float4 k1 = *(const float4*)(K + rb + 1 * ND + 4 * l15);
        const float4 v0 = *(const float4*)(V + rb + 0 * ND + 4 * l15);
        const float4 v1 = *(const float4*)(V + rb + 1 * ND + 4 * l15);

        float s0 = dot4(qv, k0), s1 = dot4(qv, k1);
        #pragma unroll
        for (int o = 8; o >= 1; o >>= 1) {
            s0 += __shfl_xor(s0, o);
            s1 += __shfl_xor(s1, o);
        }

        s0 *= 0.125f; s1 *= 0.125f;
        const float m  = fmaxf(s0, s1);
        const float e0 = __expf(s0 - m), e1 = __expf(s1 - m);
        const float rs = 1.f / (e0 + e1);
        const float w0 = e0 * rs, w1 = e1 * rs;

        const float xe0 = w0 * v0.x + w1 * v1.x;
        const float xe1 = w0 * v0.y + w1 * v1.y;
        const float xe2 = w0 * v0.z + w1 * v1.z;
        const float xe3 = w0 * v0.w + w1 * v1.w;

        *(float4*)(out + rb + 4 * l31) = make_float4(xe0, xe1, xe2, xe3);
        xs0 += xe0; xs1 += xe1; xs2 += xe2; xs3 += xe3;
    }

    // combine the two position-halves (same (q,d) in lanes l and l+32)
    xs0 += __shfl_xor(xs0, 32); xs1 += __shfl_xor(xs1, 32);
    xs2 += __shfl_xor(xs2, 32); xs3 += __shfl_xor(xs3, 32);
    if (half == 0)
        *(float4*)(partials + (size_t)wid * NPART_STRIDE + sg2 * 64 + 4 * l15) =
            make_float4(xs0, xs1, xs2, xs3);
}

__global__ __launch_bounds__(256)
void sda_pass1(const float* __restrict__ Q, const float* __restrict__ K,
               const float* __restrict__ V, float* __restrict__ out,
               float* __restrict__ partials)
{
    const int bid = blockIdx.x;
    const int w   = threadIdx.x >> 6;
    const int wid = bid * 4 + w;
    if (bid < 1024) {                      // group 0: 4 b * 256 blocks
        const int b = bid >> 8, cw = (bid & 255) * 4 + w;
        pass1_g3<0>(Q, K, V, out, partials, b, cw, wid, 1, 0, 2048);
    } else if (bid < 1536) {               // group 1: 4 b * 128 blocks
        const int loc = bid - 1024;
        const int b = loc >> 7, cw = (loc & 127) * 4 + w;
        pass1_g3<192>(Q, K, V, out, partials, b, cw, wid, 2, 1, 4096);
    } else {                               // group 2: 4 b * 64 blocks
        const int loc = bid - 1536;
        const int b = loc >> 6, cw = (loc & 63) * 4 + w;
        pass1_g2(Q, K, V, out, partials, b, cw, wid);
    }
}

// pass2a: 256 blocks = (bh 0..31) x (slice 0..7); coalesced wave-partial reduce.
__global__ __launch_bounds__(256)
void sda_pass2a(const float* __restrict__ partials, float* __restrict__ partial2)
{
    const int bid   = blockIdx.x;
    const int bh    = bid >> 3;
    const int slice = bid & 7;
    const int b     = bh >> 3;
    const int h     = bh & 7;
    const int d     = threadIdx.x & 63;
    const int part  = threadIdx.x >> 6;   // 4-way split of the slice
    int qi, wstart, cnt;
    if (h < 3)      { qi = h;     wstart = b * 1024;       cnt = 1024; }
    else if (h < 6) { qi = h - 3; wstart = 4096 + b * 512; cnt = 512;  }
    else            { qi = h - 6; wstart = 6144 + b * 256; cnt = 256;  }
    const int len = cnt >> 3;             // 128 / 64 / 32
    const int c0  = wstart + slice * len;
    float s = 0.f;
    #pragma unroll 4
    for (int c = part; c < len; c += 4)
        s += partials[(size_t)(c0 + c) * NPART_STRIDE + qi * 64 + d];
    __shared__ float sred[4][64];
    sred[part][d] = s;
    __syncthreads();
    if (part == 0)
        partial2[(size_t)bid * 64 + d] = sred[0][d] + sred[1][d] + sred[2][d] + sred[3][d];
}

// pass2b: finish 8 slice-partials per (b,h,d) -> inv
__global__ __launch_bounds__(256)
void sda_pass2b(const float* __restrict__ partial2, float* __restrict__ inv)
{
    const int t = blockIdx.x * 256 + threadIdx.x;   // 2048 = bh*64 + d
    if (t >= NB * NH * ND) return;
    const int bh = t >> 6;
    const int d  = t & 63;
    float s = 0.f;
    #pragma unroll
    for (int sl = 0; sl < 8; ++sl)
        s += partial2[(size_t)(bh * 8 + sl) * 64 + d];
    inv[t] = 1.f / (3.f * (s + 1e-8f));
}

__global__ __launch_bounds__(256)
void sda_pass3(float* __restrict__ out, const float* __restrict__ inv)
{
    const int total4 = NB * NN * NH * ND / 4;   // 4,194,304 float4s
    for (int idx = blockIdx.x * 256 + threadIdx.x; idx < total4;
         idx += gridDim.x * 256) {
        const int d4  = idx & 15;
        const int rem = idx >> 4;
        const int h   = rem & 7;
        const int pos = (rem >> 3) & 8191;
        const int b   = rem >> 16;
        const bool cov = (h < 3) || ((h < 6) ? ((pos & 1) == 1) : ((pos & 3) == 2));
        float4 o;
        if (cov) {
            const float4 v = ((const float4*)out)[idx];
            const float4 f = ((const float4*)inv)[b * 128 + h * 16 + d4];
            o = make_float4(v.x * f.x, v.y * f.y, v.z * f.z, v.w * f.w);
        } else {
            o = make_float4(0.f, 0.f, 0.f, 0.f);
        }
        ((float4*)out)[idx] = o;
    }
}

extern "C" void kernel_launch(void* const* d_in, const int* in_sizes, int n_in,
                              void* d_out, int out_size, void* d_ws, size_t ws_size,
                              hipStream_t stream)
{
    const float* Q = (const float*)d_in[0];
    const float* K = (const float*)d_in[1];
    const float* V = (const float*)d_in[2];
    float* out      = (float*)d_out;
    float* partials = (float*)d_ws;                              // 7168*192*4 ≈ 5.5 MB
    float* partial2 = partials + (size_t)N_WAVES_P1 * NPART_STRIDE; // +16384 floats
    float* inv      = partial2 + 256 * 64;                       // +2048 floats

    hipLaunchKernelGGL(sda_pass1,  dim3(N_BLOCKS_P1), dim3(256), 0, stream,
                       Q, K, V, out, partials);
    hipLaunchKernelGGL(sda_pass2a, dim3(256), dim3(256), 0, stream, partials, partial2);
    hipLaunchKernelGGL(sda_pass2b, dim3(8),   dim3(256), 0, stream, partial2, inv);
    hipLaunchKernelGGL(sda_pass3,  dim3(2048), dim3(256), 0, stream, out, inv);
}